// Round 3
// baseline (16322.824 us; speedup 1.0000x reference)
//
#include <hip/hip_runtime.h>
#include <hip/hip_bf16.h>

#define EMB      128
#define N_NODES_ 50000
#define N_EDGES_ 800000
#define N_GRAPH_ 256
#define NLAYER_  5

__device__ __forceinline__ float silu_f(float x) {
    return x / (1.0f + __expf(-x));
}

// bf16 <-> f32 via bit ops (RNE), avoids __hip_bfloat16 API differences
__device__ __forceinline__ float bf2f(unsigned short h) {
    return __uint_as_float(((unsigned)h) << 16);
}
__device__ __forceinline__ unsigned short f2bf(float f) {
    unsigned u = __float_as_uint(f);
    unsigned r = 0x7FFFu + ((u >> 16) & 1u);
    return (unsigned short)((u + r) >> 16);
}

// edge-state storage abstraction: T = float (fp32 path) or unsigned short
// (bf16 path). NOTE: named EdgeSt — "EIO" collides with the errno macro.
template <typename T> struct EdgeSt;
template <> struct EdgeSt<float> {
    static __device__ __forceinline__ float4 load4(const float* p) { return *(const float4*)p; }
    static __device__ __forceinline__ void store4(float* p, float4 v) { *(float4*)p = v; }
    static __device__ __forceinline__ void store1(float* p, float v) { *p = v; }
};
template <> struct EdgeSt<unsigned short> {
    static __device__ __forceinline__ float4 load4(const unsigned short* p) {
        ushort4 u = *(const ushort4*)p;  // 8B aligned: all offsets are multiples of 4 elems
        return make_float4(bf2f(u.x), bf2f(u.y), bf2f(u.z), bf2f(u.w));
    }
    static __device__ __forceinline__ void store4(unsigned short* p, float4 v) {
        ushort4 u = make_ushort4(f2bf(v.x), f2bf(v.y), f2bf(v.z), f2bf(v.w));
        *(ushort4*)p = u;
    }
    static __device__ __forceinline__ void store1(unsigned short* p, float v) { *p = f2bf(v); }
};

__device__ __forceinline__ void fma4x4(const float4 a[4], const float4& w0, const float4& w1,
                                       const float4& w2, const float4& w3, float acc[4][4]) {
#pragma unroll
    for (int i = 0; i < 4; ++i) {
        acc[i][0] = fmaf(a[i].x, w0.x, fmaf(a[i].y, w1.x, fmaf(a[i].z, w2.x, fmaf(a[i].w, w3.x, acc[i][0]))));
        acc[i][1] = fmaf(a[i].x, w0.y, fmaf(a[i].y, w1.y, fmaf(a[i].z, w2.y, fmaf(a[i].w, w3.y, acc[i][1]))));
        acc[i][2] = fmaf(a[i].x, w0.z, fmaf(a[i].y, w1.z, fmaf(a[i].z, w2.z, fmaf(a[i].w, w3.z, acc[i][2]))));
        acc[i][3] = fmaf(a[i].x, w0.w, fmaf(a[i].y, w1.w, fmaf(a[i].z, w2.w, fmaf(a[i].w, w3.w, acc[i][3]))));
    }
}

// ---------------------------------------------------------------------------
// Fused 5-matmul edge MLP + residual + fused scatter-add aggregation.
// One block = 32 edges. m [32][384] in LDS (stride 388). fp32 compute; h_edge
// state stored as T. Weights straight from L1/L2 (per-layer set = 448 KB).
// ---------------------------------------------------------------------------
template <typename T>
__global__ __launch_bounds__(256, 2) void edge_mlp_kernel(
    const float* __restrict__ h_node, T* __restrict__ h_edge,
    float* __restrict__ agg,
    const int* __restrict__ row, const int* __restrict__ col,
    const float* __restrict__ W0, const float* __restrict__ b0,     // [384][128],[128]
    const float* __restrict__ Wh, const float* __restrict__ bh)     // [4][128][128],[4][128]
{
    __shared__ __align__(16) float A[32][388];
    __shared__ int rv[32], cv[32];
    const int tid = threadIdx.x;
    const int e0 = blockIdx.x * 32;

    if (tid < 32) { rv[tid] = row[e0 + tid]; cv[tid] = col[e0 + tid]; }
    __syncthreads();

    // build m0 = concat(h_edge[e], h_node[row], h_node[col]) — 4-wide
    for (int idx = tid; idx < 32 * 96; idx += 256) {
        int t = idx / 96;
        int k = (idx - t * 96) << 2;
        float4 v;
        if (k < 128)      v = EdgeSt<T>::load4(&h_edge[(size_t)(e0 + t) * 128 + k]);
        else if (k < 256) v = *(const float4*)&h_node[(size_t)rv[t] * 128 + (k - 128)];
        else              v = *(const float4*)&h_node[(size_t)cv[t] * 128 + (k - 256)];
        *(float4*)&A[t][k] = v;
    }
    __syncthreads();

    const int r = tid >> 5, c = tid & 31;
    const int t0 = r << 2, j0 = c << 2;
    float res[4][4];

    for (int stage = 0; stage < 5; ++stage) {
        const float* __restrict__ W  = (stage == 0) ? W0 : (Wh + (size_t)(stage - 1) * 128 * 128);
        const float* __restrict__ bb = (stage == 0) ? b0 : (bh + (size_t)(stage - 1) * 128);
        const int K = (stage == 0) ? 384 : 128;

        float acc[4][4] = {{0.f, 0.f, 0.f, 0.f}};
#pragma unroll 2
        for (int kk = 0; kk < K; kk += 4) {
            float4 a[4];
#pragma unroll
            for (int i = 0; i < 4; ++i) a[i] = *(const float4*)&A[t0 + i][kk];
            const float4 w0 = *(const float4*)&W[(size_t)(kk + 0) * 128 + j0];
            const float4 w1 = *(const float4*)&W[(size_t)(kk + 1) * 128 + j0];
            const float4 w2 = *(const float4*)&W[(size_t)(kk + 2) * 128 + j0];
            const float4 w3 = *(const float4*)&W[(size_t)(kk + 3) * 128 + j0];
            fma4x4(a, w0, w1, w2, w3, acc);
        }
        const float4 bv = *(const float4*)&bb[j0];
        const float bias[4] = {bv.x, bv.y, bv.z, bv.w};
#pragma unroll
        for (int i = 0; i < 4; ++i)
#pragma unroll
            for (int jj = 0; jj < 4; ++jj)
                res[i][jj] = silu_f(acc[i][jj] + bias[jj]);
        if (stage < 4) {
            __syncthreads();   // all reads of A for this stage done
#pragma unroll
            for (int i = 0; i < 4; ++i)
                *(float4*)&A[t0 + i][j0] = make_float4(res[i][0], res[i][1], res[i][2], res[i][3]);
            __syncthreads();
        }
    }

    // epilogue: h_edge += m ; agg[row] += h_edge_new
#pragma unroll
    for (int i = 0; i < 4; ++i) {
        const size_t eoff = (size_t)(e0 + t0 + i) * 128 + j0;
        float4 he = EdgeSt<T>::load4(&h_edge[eoff]);
        he.x += res[i][0]; he.y += res[i][1]; he.z += res[i][2]; he.w += res[i][3];
        EdgeSt<T>::store4(&h_edge[eoff], he);
        float* ap = &agg[(size_t)rv[t0 + i] * 128 + j0];
        atomicAdd(ap + 0, he.x);
        atomicAdd(ap + 1, he.y);
        atomicAdd(ap + 2, he.z);
        atomicAdd(ap + 3, he.w);
    }
}

// ---------------------------------------------------------------------------
// Generic [N,128] @ [128,128] (+bias, optional gather / silu / residual-add).
// ---------------------------------------------------------------------------
template <int GATHER, int RESID, int SILU>
__global__ __launch_bounds__(256, 4) void row_gemm_kernel(
    const float* __restrict__ src, const int* __restrict__ gidx,
    const float* __restrict__ W, const float* __restrict__ bias,
    float* __restrict__ dst, int N)
{
    __shared__ __align__(16) float A[32][132];
    const int tid = threadIdx.x;
    const int n0 = blockIdx.x * 32;

    for (int idx = tid; idx < 32 * 32; idx += 256) {
        int t = idx >> 5, k = (idx & 31) << 2;
        int n = n0 + t;
        float4 v = make_float4(0.f, 0.f, 0.f, 0.f);
        if (n < N) {
            int rr = GATHER ? gidx[n] : n;
            v = *(const float4*)&src[(size_t)rr * 128 + k];
        }
        *(float4*)&A[t][k] = v;
    }
    __syncthreads();

    const int r = tid >> 5, c = tid & 31;
    const int t0 = r << 2, j0 = c << 2;
    float acc[4][4] = {{0.f, 0.f, 0.f, 0.f}};
#pragma unroll 2
    for (int kk = 0; kk < 128; kk += 4) {
        float4 a[4];
#pragma unroll
        for (int i = 0; i < 4; ++i) a[i] = *(const float4*)&A[t0 + i][kk];
        const float4 w0 = *(const float4*)&W[(size_t)(kk + 0) * 128 + j0];
        const float4 w1 = *(const float4*)&W[(size_t)(kk + 1) * 128 + j0];
        const float4 w2 = *(const float4*)&W[(size_t)(kk + 2) * 128 + j0];
        const float4 w3 = *(const float4*)&W[(size_t)(kk + 3) * 128 + j0];
        fma4x4(a, w0, w1, w2, w3, acc);
    }
    const float4 bv = *(const float4*)&bias[j0];
    const float bias4[4] = {bv.x, bv.y, bv.z, bv.w};
#pragma unroll
    for (int i = 0; i < 4; ++i) {
        int n = n0 + t0 + i;
        if (n >= N) continue;
        float x[4];
#pragma unroll
        for (int jj = 0; jj < 4; ++jj) {
            x[jj] = acc[i][jj] + bias4[jj];
            if (SILU) x[jj] = silu_f(x[jj]);
        }
        const size_t off = (size_t)n * 128 + j0;
        float4 o = make_float4(x[0], x[1], x[2], x[3]);
        if (RESID) {
            float4 d = *(const float4*)&dst[off];
            o.x += d.x; o.y += d.y; o.z += d.z; o.w += d.w;
        }
        *(float4*)&dst[off] = o;
    }
}

// ---------------------------------------------------------------------------
// Edge embedding: d = |pos[row]-pos[col]|, 32 gaussians, @ edge_emb_w + b.
// ---------------------------------------------------------------------------
template <typename T>
__global__ __launch_bounds__(256) void edge_embed_kernel(
    const float* __restrict__ pos, const int* __restrict__ row, const int* __restrict__ col,
    const float* __restrict__ Wemb, const float* __restrict__ bemb,
    T* __restrict__ h_edge, int E)
{
    __shared__ __align__(16) float Ws[32][128];
    __shared__ float bas[8][32];
    const int tid = threadIdx.x;
    {
        const float4* Wv = (const float4*)Wemb;
        float4* Wsv = (float4*)Ws;
        for (int idx = tid; idx < 1024; idx += 256) Wsv[idx] = Wv[idx];
    }
    const int g = tid >> 5, k = tid & 31;
    const int j = tid & 127, gh = tid >> 7;
    const float mu   = (float)k * (5.0f / 31.0f);  // linspace(0, CUT, BINS) inclusive
    const float invs = 32.0f / 5.0f;               // 1/sigma, sigma = CUT/BINS

    for (int eb = blockIdx.x * 8; eb < E; eb += gridDim.x * 8) {
        __syncthreads();  // Ws ready (1st iter) / prior readers of bas done
        const int e = eb + g;
        const int rr = row[e], cc = col[e];
        const float dx = pos[rr * 3 + 0] - pos[cc * 3 + 0];
        const float dy = pos[rr * 3 + 1] - pos[cc * 3 + 1];
        const float dz = pos[rr * 3 + 2] - pos[cc * 3 + 2];
        const float d = sqrtf(dx * dx + dy * dy + dz * dz);
        const float t = (d - mu) * invs;
        bas[g][k] = __expf(-0.5f * t * t);
        __syncthreads();
#pragma unroll
        for (int gg = 0; gg < 4; ++gg) {
            const int ge = (gh << 2) + gg;
            float h = bemb[j];
#pragma unroll
            for (int kk = 0; kk < 32; ++kk) h = fmaf(bas[ge][kk], Ws[kk][j], h);
            EdgeSt<T>::store1(&h_edge[(size_t)(eb + ge) * 128 + j], h);
        }
    }
}

// ---------------------------------------------------------------------------
// Graph pooling: batch is sorted -> run-length accumulate, flush on change.
// ---------------------------------------------------------------------------
__global__ __launch_bounds__(128) void pool_kernel(
    const float* __restrict__ h_node, const int* __restrict__ batch,
    float* __restrict__ sums, float* __restrict__ cnt, int N)
{
    __shared__ int bb[256];
    const int tid = threadIdx.x;
    const int n0 = blockIdx.x * 256;
    for (int idx = tid; idx < 256; idx += 128) {
        int n = n0 + idx;
        bb[idx] = (n < N) ? batch[n] : -1;
    }
    __syncthreads();
    int cur = bb[0];
    float run = 0.f, runc = 0.f;
    for (int i = 0; i < 256; ++i) {
        const int b = bb[i];
        if (b < 0) break;                 // uniform across block
        if (b != cur) {
            atomicAdd(&sums[(size_t)cur * 128 + tid], run);
            if (tid == 0) atomicAdd(&cnt[cur], runc);
            run = 0.f; runc = 0.f; cur = b;
        }
        run += h_node[(size_t)(n0 + i) * 128 + tid];
        runc += 1.f;
    }
    atomicAdd(&sums[(size_t)cur * 128 + tid], run);
    if (tid == 0) atomicAdd(&cnt[cur], runc);
}

__global__ __launch_bounds__(256) void final_kernel(
    const float* __restrict__ sums, const float* __restrict__ cnt,
    const float* __restrict__ out_w, const float* __restrict__ out_b,
    float* __restrict__ out)
{
    const int g = threadIdx.x;  // 256 graphs
    const float c = fmaxf(cnt[g], 1.0f);
    float acc = 0.f;
    for (int jj = 0; jj < 128; ++jj) acc = fmaf(sums[(size_t)g * 128 + jj], out_w[jj], acc);
    out[g] = acc / c + out_b[0];
}

__global__ void zero_out_kernel(float* out, int n) {
    int i = blockIdx.x * 256 + threadIdx.x;
    if (i < n) out[i] = 0.f;
}

// ---------------------------------------------------------------------------

template <typename T>
static void run_all(void* const* d_in, void* d_out, void* d_ws, hipStream_t stream)
{
    const int*   z          = (const int*)  d_in[0];
    const float* pos        = (const float*)d_in[1];
    const int*   batch      = (const int*)  d_in[2];
    const int*   eidx       = (const int*)  d_in[3];
    const float* atom_table = (const float*)d_in[4];
    const float* atom_w     = (const float*)d_in[5];
    const float* atom_b     = (const float*)d_in[6];
    const float* edge_emb_w = (const float*)d_in[7];
    const float* edge_emb_b = (const float*)d_in[8];
    const float* edge_w0    = (const float*)d_in[9];    // [5][384][128]
    const float* edge_b0    = (const float*)d_in[10];   // [5][128]
    const float* edge_w     = (const float*)d_in[11];   // [5][4][128][128]
    const float* edge_b     = (const float*)d_in[12];   // [5][4][128]
    const float* node_w     = (const float*)d_in[13];   // [5][128][128]
    const float* node_b     = (const float*)d_in[14];   // [5][128]
    const float* out_w      = (const float*)d_in[15];
    const float* out_b      = (const float*)d_in[16];
    const int* row = eidx;
    const int* col = eidx + N_EDGES_;

    // workspace: h_node | agg | pool_sums | pool_cnt | h_edge(T)
    float* ws     = (float*)d_ws;
    float* h_node = ws;                                        // 50000*128 f32
    float* aggb   = h_node + (size_t)N_NODES_ * EMB;           // 50000*128 f32
    float* sums   = aggb   + (size_t)N_NODES_ * EMB;           // 256*128 f32
    float* cnt    = sums   + (size_t)N_GRAPH_ * EMB;           // 256 f32
    T*     h_edge = (T*)(cnt + N_GRAPH_);                      // 800000*128 T (16B-aligned)

    const int grid_rows = (N_NODES_ + 31) / 32;                // 1563

    row_gemm_kernel<1, 0, 0><<<grid_rows, 256, 0, stream>>>(atom_table, z, atom_w, atom_b, h_node, N_NODES_);
    edge_embed_kernel<T><<<1024, 256, 0, stream>>>(pos, row, col, edge_emb_w, edge_emb_b, h_edge, N_EDGES_);

    for (int l = 0; l < NLAYER_; ++l) {
        (void)hipMemsetAsync(aggb, 0, (size_t)N_NODES_ * EMB * sizeof(float), stream);
        edge_mlp_kernel<T><<<N_EDGES_ / 32, 256, 0, stream>>>(
            h_node, h_edge, aggb, row, col,
            edge_w0 + (size_t)l * 384 * 128, edge_b0 + (size_t)l * 128,
            edge_w  + (size_t)l * 4 * 128 * 128, edge_b + (size_t)l * 4 * 128);
        row_gemm_kernel<0, 1, 1><<<grid_rows, 256, 0, stream>>>(
            aggb, nullptr, node_w + (size_t)l * 128 * 128, node_b + (size_t)l * 128, h_node, N_NODES_);
    }

    (void)hipMemsetAsync(sums, 0, ((size_t)N_GRAPH_ * EMB + N_GRAPH_) * sizeof(float), stream);
    pool_kernel<<<(N_NODES_ + 255) / 256, 128, 0, stream>>>(h_node, batch, sums, cnt, N_NODES_);
    final_kernel<<<1, 256, 0, stream>>>(sums, cnt, out_w, out_b, (float*)d_out);
}

extern "C" void kernel_launch(void* const* d_in, const int* in_sizes, int n_in,
                              void* d_out, int out_size, void* d_ws, size_t ws_size,
                              hipStream_t stream)
{
    const size_t headB  = ((size_t)N_NODES_ * EMB * 2 + (size_t)N_GRAPH_ * EMB + N_GRAPH_) * sizeof(float);
    const size_t edgeE  = (size_t)N_EDGES_ * EMB;
    const size_t need_f32  = headB + edgeE * sizeof(float);          // 460,932,096 B
    const size_t need_bf16 = headB + edgeE * sizeof(unsigned short); // 256,132,096 B

    if (ws_size >= need_f32) {
        run_all<float>(d_in, d_out, d_ws, stream);
    } else if (ws_size >= need_bf16) {
        run_all<unsigned short>(d_in, d_out, d_ws, stream);
    } else {
        // ws too small even for bf16 edge state: fail cleanly (absmax = ref max),
        // distinguishing "ws exhausted" from a kernel-side fault.
        zero_out_kernel<<<1, 256, 0, stream>>>((float*)d_out, 256);
    }
}

// Round 4
// 15489.880 us; speedup vs baseline: 1.0538x; 1.0538x over previous
//
#include <hip/hip_runtime.h>

#define EMB      128
#define N_NODES_ 50000
#define N_EDGES_ 800000
#define N_GRAPH_ 256
#define NLAYER_  5

typedef short short8 __attribute__((ext_vector_type(8)));
typedef float floatx4 __attribute__((ext_vector_type(4)));

__device__ __forceinline__ float silu_f(float x) {
    return x / (1.0f + __expf(-x));
}
__device__ __forceinline__ float bf2f(unsigned short h) {
    return __uint_as_float(((unsigned)h) << 16);
}
__device__ __forceinline__ unsigned short f2bf(float f) {
    unsigned u = __float_as_uint(f);
    unsigned r = 0x7FFFu + ((u >> 16) & 1u);
    return (unsigned short)((u + r) >> 16);
}

// ---------------------------------------------------------------------------
// Weight packing: fp32 [K][128] -> bf16 B-fragment order for 16x16x32 MFMA.
// packed[tile t][kb][lane][j] = W[kb*32 + (lane>>4)*8 + j][t*16 + (lane&15)]
// Layer stride 114688 elems; stage offsets: s0=0, s>=1: 49152+(s-1)*16384.
// ---------------------------------------------------------------------------
__global__ __launch_bounds__(256) void pack_w_kernel(
    const float* __restrict__ edge_w0, const float* __restrict__ edge_w,
    unsigned short* __restrict__ Wp)
{
    const int bid = blockIdx.x;            // 200 = 5 layers * 5 stages * 8 tiles
    const int l = bid / 40, r = bid % 40, s = r / 8, t = r % 8;
    const int Kb = (s == 0) ? 12 : 4;
    const float* __restrict__ src = (s == 0)
        ? edge_w0 + (size_t)l * 384 * 128
        : edge_w  + ((size_t)l * 4 + (s - 1)) * 128 * 128;
    unsigned short* __restrict__ dst =
        Wp + (size_t)l * 114688 + ((s == 0) ? 0 : (49152 + (s - 1) * 16384)) + (size_t)t * Kb * 512;
    const int n = Kb * 512;
    for (int p = threadIdx.x; p < n; p += 256) {
        const int j = p & 7, lane = (p >> 3) & 63, kb = p >> 9;
        const int k  = kb * 32 + ((lane >> 4) << 3) + j;
        const int nn = t * 16 + (lane & 15);
        dst[p] = f2bf(src[(size_t)k * 128 + nn]);
    }
}

// ---------------------------------------------------------------------------
// MFMA edge MLP: 64 edges/block, 4 waves. A (concat, bf16) in LDS stride 392.
// Wave w computes n-tiles {2w,2w+1} x m-tiles {0..3} via mfma_f32_16x16x32_bf16.
// Stage outputs silu'd back to LDS (C-layout -> A-layout). Vectorized epilogue
// with fp32 residual + scatter atomics.
// ---------------------------------------------------------------------------
__global__ __launch_bounds__(256, 3) void edge_mlp_mfma_kernel(
    const float* __restrict__ h_node, unsigned short* __restrict__ h_edge,
    float* __restrict__ agg,
    const int* __restrict__ row, const int* __restrict__ col,
    const unsigned short* __restrict__ Wp,     // this layer's packed weights
    const float* __restrict__ b0, const float* __restrict__ bh)
{
    __shared__ unsigned short A[64][392];      // 50,176 B; rows 784 B (16B-mult)
    __shared__ int rv[64], cv[64];
    const int tid = threadIdx.x;
    const int e0 = blockIdx.x * 64;

    if (tid < 64) { rv[tid] = row[e0 + tid]; cv[tid] = col[e0 + tid]; }
    __syncthreads();

    // stage concat -> bf16 LDS: cols [0,128)=h_edge, [128,256)=h_node[row], [256,384)=h_node[col]
    for (int idx = tid; idx < 64 * 48; idx += 256) {
        const int t  = idx / 48;
        const int k8 = (idx % 48) << 3;
        if (k8 < 128) {
            *(short8*)&A[t][k8] = *(const short8*)&h_edge[(size_t)(e0 + t) * 128 + k8];
        } else {
            const float* src = (k8 < 256) ? &h_node[(size_t)rv[t] * 128 + (k8 - 128)]
                                          : &h_node[(size_t)cv[t] * 128 + (k8 - 256)];
            const float4 f0 = *(const float4*)src;
            const float4 f1 = *(const float4*)(src + 4);
            short8 v;
            v[0] = (short)f2bf(f0.x); v[1] = (short)f2bf(f0.y);
            v[2] = (short)f2bf(f0.z); v[3] = (short)f2bf(f0.w);
            v[4] = (short)f2bf(f1.x); v[5] = (short)f2bf(f1.y);
            v[6] = (short)f2bf(f1.z); v[7] = (short)f2bf(f1.w);
            *(short8*)&A[t][k8] = v;
        }
    }
    __syncthreads();

    const int lane = tid & 63;
    const int wv   = tid >> 6;
    const int lr   = lane & 15;   // A row-in-tile / C col
    const int lg   = lane >> 4;   // k-group / C row-group
    const int nt0  = 2 * wv, nt1 = 2 * wv + 1;

    for (int s = 0; s < 5; ++s) {
        const int Kb = (s == 0) ? 12 : 4;
        const unsigned short* __restrict__ Ws =
            Wp + ((s == 0) ? 0 : (49152 + (s - 1) * 16384));
        const float* __restrict__ bias = (s == 0) ? b0 : (bh + (s - 1) * 128);

        floatx4 acc[4][2];
#pragma unroll
        for (int mt = 0; mt < 4; ++mt) {
            acc[mt][0] = (floatx4){0.f, 0.f, 0.f, 0.f};
            acc[mt][1] = (floatx4){0.f, 0.f, 0.f, 0.f};
        }

        const unsigned short* bptr0 = Ws + ((size_t)(nt0 * Kb) * 64 + lane) * 8;
        const unsigned short* bptr1 = Ws + ((size_t)(nt1 * Kb) * 64 + lane) * 8;
#pragma unroll 2
        for (int kb = 0; kb < Kb; ++kb) {
            const short8 bf0 = *(const short8*)(bptr0 + (size_t)kb * 512);
            const short8 bf1 = *(const short8*)(bptr1 + (size_t)kb * 512);
#pragma unroll
            for (int mt = 0; mt < 4; ++mt) {
                const short8 af = *(const short8*)&A[mt * 16 + lr][kb * 32 + lg * 8];
                acc[mt][0] = __builtin_amdgcn_mfma_f32_16x16x32_bf16(af, bf0, acc[mt][0], 0, 0, 0);
                acc[mt][1] = __builtin_amdgcn_mfma_f32_16x16x32_bf16(af, bf1, acc[mt][1], 0, 0, 0);
            }
        }
        const float bn0 = bias[nt0 * 16 + lr];
        const float bn1 = bias[nt1 * 16 + lr];
        __syncthreads();   // all LDS reads of this stage done before overwrite
#pragma unroll
        for (int mt = 0; mt < 4; ++mt)
#pragma unroll
            for (int r4 = 0; r4 < 4; ++r4) {
                const int m = mt * 16 + lg * 4 + r4;
                A[m][nt0 * 16 + lr] = f2bf(silu_f(acc[mt][0][r4] + bn0));
                A[m][nt1 * 16 + lr] = f2bf(silu_f(acc[mt][1][r4] + bn1));
            }
        __syncthreads();
    }

    // epilogue: h_edge += m ; agg[row] += h_edge_new   (vectorized b128)
    for (int idx = tid; idx < 64 * 16; idx += 256) {
        const int t  = idx >> 4;
        const int k8 = (idx & 15) << 3;
        const size_t eoff = (size_t)(e0 + t) * 128 + k8;
        const short8 mv = *(const short8*)&A[t][k8];
        const short8 ov = *(const short8*)&h_edge[eoff];
        float he[8];
        short8 sv;
#pragma unroll
        for (int i = 0; i < 8; ++i) {
            he[i] = bf2f((unsigned short)ov[i]) + bf2f((unsigned short)mv[i]);
            sv[i] = (short)f2bf(he[i]);
        }
        *(short8*)&h_edge[eoff] = sv;
        float* ap = &agg[(size_t)rv[t] * 128 + k8];
#pragma unroll
        for (int i = 0; i < 8; ++i) atomicAdd(ap + i, he[i]);
    }
}

// ---------------------------------------------------------------------------
// Fallback VALU edge MLP (round-3, bf16 state) for small-ws case.
// ---------------------------------------------------------------------------
__device__ __forceinline__ float4 ld_bf4(const unsigned short* p) {
    ushort4 u = *(const ushort4*)p;
    return make_float4(bf2f(u.x), bf2f(u.y), bf2f(u.z), bf2f(u.w));
}
__device__ __forceinline__ void st_bf4(unsigned short* p, float4 v) {
    *(ushort4*)p = make_ushort4(f2bf(v.x), f2bf(v.y), f2bf(v.z), f2bf(v.w));
}

__device__ __forceinline__ void fma4x4(const float4 a[4], const float4& w0, const float4& w1,
                                       const float4& w2, const float4& w3, float acc[4][4]) {
#pragma unroll
    for (int i = 0; i < 4; ++i) {
        acc[i][0] = fmaf(a[i].x, w0.x, fmaf(a[i].y, w1.x, fmaf(a[i].z, w2.x, fmaf(a[i].w, w3.x, acc[i][0]))));
        acc[i][1] = fmaf(a[i].x, w0.y, fmaf(a[i].y, w1.y, fmaf(a[i].z, w2.y, fmaf(a[i].w, w3.y, acc[i][1]))));
        acc[i][2] = fmaf(a[i].x, w0.z, fmaf(a[i].y, w1.z, fmaf(a[i].z, w2.z, fmaf(a[i].w, w3.z, acc[i][2]))));
        acc[i][3] = fmaf(a[i].x, w0.w, fmaf(a[i].y, w1.w, fmaf(a[i].z, w2.w, fmaf(a[i].w, w3.w, acc[i][3]))));
    }
}

__global__ __launch_bounds__(256, 2) void edge_mlp_fallback_kernel(
    const float* __restrict__ h_node, unsigned short* __restrict__ h_edge,
    float* __restrict__ agg,
    const int* __restrict__ row, const int* __restrict__ col,
    const float* __restrict__ W0, const float* __restrict__ b0,
    const float* __restrict__ Wh, const float* __restrict__ bh)
{
    __shared__ __align__(16) float A[32][388];
    __shared__ int rv[32], cv[32];
    const int tid = threadIdx.x;
    const int e0 = blockIdx.x * 32;

    if (tid < 32) { rv[tid] = row[e0 + tid]; cv[tid] = col[e0 + tid]; }
    __syncthreads();

    for (int idx = tid; idx < 32 * 96; idx += 256) {
        int t = idx / 96;
        int k = (idx - t * 96) << 2;
        float4 v;
        if (k < 128)      v = ld_bf4(&h_edge[(size_t)(e0 + t) * 128 + k]);
        else if (k < 256) v = *(const float4*)&h_node[(size_t)rv[t] * 128 + (k - 128)];
        else              v = *(const float4*)&h_node[(size_t)cv[t] * 128 + (k - 256)];
        *(float4*)&A[t][k] = v;
    }
    __syncthreads();

    const int r = tid >> 5, c = tid & 31;
    const int t0 = r << 2, j0 = c << 2;
    float res[4][4];

    for (int stage = 0; stage < 5; ++stage) {
        const float* __restrict__ W  = (stage == 0) ? W0 : (Wh + (size_t)(stage - 1) * 128 * 128);
        const float* __restrict__ bb = (stage == 0) ? b0 : (bh + (size_t)(stage - 1) * 128);
        const int K = (stage == 0) ? 384 : 128;

        float acc[4][4] = {{0.f, 0.f, 0.f, 0.f}};
#pragma unroll 2
        for (int kk = 0; kk < K; kk += 4) {
            float4 a[4];
#pragma unroll
            for (int i = 0; i < 4; ++i) a[i] = *(const float4*)&A[t0 + i][kk];
            const float4 w0 = *(const float4*)&W[(size_t)(kk + 0) * 128 + j0];
            const float4 w1 = *(const float4*)&W[(size_t)(kk + 1) * 128 + j0];
            const float4 w2 = *(const float4*)&W[(size_t)(kk + 2) * 128 + j0];
            const float4 w3 = *(const float4*)&W[(size_t)(kk + 3) * 128 + j0];
            fma4x4(a, w0, w1, w2, w3, acc);
        }
        const float4 bv = *(const float4*)&bb[j0];
        const float bias[4] = {bv.x, bv.y, bv.z, bv.w};
#pragma unroll
        for (int i = 0; i < 4; ++i)
#pragma unroll
            for (int jj = 0; jj < 4; ++jj)
                res[i][jj] = silu_f(acc[i][jj] + bias[jj]);
        if (stage < 4) {
            __syncthreads();
#pragma unroll
            for (int i = 0; i < 4; ++i)
                *(float4*)&A[t0 + i][j0] = make_float4(res[i][0], res[i][1], res[i][2], res[i][3]);
            __syncthreads();
        }
    }

#pragma unroll
    for (int i = 0; i < 4; ++i) {
        const size_t eoff = (size_t)(e0 + t0 + i) * 128 + j0;
        float4 he = ld_bf4(&h_edge[eoff]);
        he.x += res[i][0]; he.y += res[i][1]; he.z += res[i][2]; he.w += res[i][3];
        st_bf4(&h_edge[eoff], he);
        float* ap = &agg[(size_t)rv[t0 + i] * 128 + j0];
        atomicAdd(ap + 0, he.x);
        atomicAdd(ap + 1, he.y);
        atomicAdd(ap + 2, he.z);
        atomicAdd(ap + 3, he.w);
    }
}

// ---------------------------------------------------------------------------
// Generic [N,128] @ [128,128] (+bias, optional gather / silu / residual-add).
// ---------------------------------------------------------------------------
template <int GATHER, int RESID, int SILU>
__global__ __launch_bounds__(256, 4) void row_gemm_kernel(
    const float* __restrict__ src, const int* __restrict__ gidx,
    const float* __restrict__ W, const float* __restrict__ bias,
    float* __restrict__ dst, int N)
{
    __shared__ __align__(16) float A[32][132];
    const int tid = threadIdx.x;
    const int n0 = blockIdx.x * 32;

    for (int idx = tid; idx < 32 * 32; idx += 256) {
        int t = idx >> 5, k = (idx & 31) << 2;
        int n = n0 + t;
        float4 v = make_float4(0.f, 0.f, 0.f, 0.f);
        if (n < N) {
            int rr = GATHER ? gidx[n] : n;
            v = *(const float4*)&src[(size_t)rr * 128 + k];
        }
        *(float4*)&A[t][k] = v;
    }
    __syncthreads();

    const int r = tid >> 5, c = tid & 31;
    const int t0 = r << 2, j0 = c << 2;
    float acc[4][4] = {{0.f, 0.f, 0.f, 0.f}};
#pragma unroll 2
    for (int kk = 0; kk < 128; kk += 4) {
        float4 a[4];
#pragma unroll
        for (int i = 0; i < 4; ++i) a[i] = *(const float4*)&A[t0 + i][kk];
        const float4 w0 = *(const float4*)&W[(size_t)(kk + 0) * 128 + j0];
        const float4 w1 = *(const float4*)&W[(size_t)(kk + 1) * 128 + j0];
        const float4 w2 = *(const float4*)&W[(size_t)(kk + 2) * 128 + j0];
        const float4 w3 = *(const float4*)&W[(size_t)(kk + 3) * 128 + j0];
        fma4x4(a, w0, w1, w2, w3, acc);
    }
    const float4 bv = *(const float4*)&bias[j0];
    const float bias4[4] = {bv.x, bv.y, bv.z, bv.w};
#pragma unroll
    for (int i = 0; i < 4; ++i) {
        int n = n0 + t0 + i;
        if (n >= N) continue;
        float x[4];
#pragma unroll
        for (int jj = 0; jj < 4; ++jj) {
            x[jj] = acc[i][jj] + bias4[jj];
            if (SILU) x[jj] = silu_f(x[jj]);
        }
        const size_t off = (size_t)n * 128 + j0;
        float4 o = make_float4(x[0], x[1], x[2], x[3]);
        if (RESID) {
            float4 d = *(const float4*)&dst[off];
            o.x += d.x; o.y += d.y; o.z += d.z; o.w += d.w;
        }
        *(float4*)&dst[off] = o;
    }
}

// ---------------------------------------------------------------------------
// Edge embedding: d = |pos[row]-pos[col]|, 32 gaussians, @ edge_emb_w + b.
// ---------------------------------------------------------------------------
__global__ __launch_bounds__(256) void edge_embed_kernel(
    const float* __restrict__ pos, const int* __restrict__ row, const int* __restrict__ col,
    const float* __restrict__ Wemb, const float* __restrict__ bemb,
    unsigned short* __restrict__ h_edge, int E)
{
    __shared__ __align__(16) float Ws[32][128];
    __shared__ float bas[8][32];
    const int tid = threadIdx.x;
    {
        const float4* Wv = (const float4*)Wemb;
        float4* Wsv = (float4*)Ws;
        for (int idx = tid; idx < 1024; idx += 256) Wsv[idx] = Wv[idx];
    }
    const int g = tid >> 5, k = tid & 31;
    const int j = tid & 127, gh = tid >> 7;
    const float mu   = (float)k * (5.0f / 31.0f);
    const float invs = 32.0f / 5.0f;

    for (int eb = blockIdx.x * 8; eb < E; eb += gridDim.x * 8) {
        __syncthreads();
        const int e = eb + g;
        const int rr = row[e], cc = col[e];
        const float dx = pos[rr * 3 + 0] - pos[cc * 3 + 0];
        const float dy = pos[rr * 3 + 1] - pos[cc * 3 + 1];
        const float dz = pos[rr * 3 + 2] - pos[cc * 3 + 2];
        const float d = sqrtf(dx * dx + dy * dy + dz * dz);
        const float t = (d - mu) * invs;
        bas[g][k] = __expf(-0.5f * t * t);
        __syncthreads();
#pragma unroll
        for (int gg = 0; gg < 4; ++gg) {
            const int ge = (gh << 2) + gg;
            float h = bemb[j];
#pragma unroll
            for (int kk = 0; kk < 32; ++kk) h = fmaf(bas[ge][kk], Ws[kk][j], h);
            h_edge[(size_t)(eb + ge) * 128 + j] = f2bf(h);
        }
    }
}

// ---------------------------------------------------------------------------
// Graph pooling + output head.
// ---------------------------------------------------------------------------
__global__ __launch_bounds__(128) void pool_kernel(
    const float* __restrict__ h_node, const int* __restrict__ batch,
    float* __restrict__ sums, float* __restrict__ cnt, int N)
{
    __shared__ int bb[256];
    const int tid = threadIdx.x;
    const int n0 = blockIdx.x * 256;
    for (int idx = tid; idx < 256; idx += 128) {
        int n = n0 + idx;
        bb[idx] = (n < N) ? batch[n] : -1;
    }
    __syncthreads();
    int cur = bb[0];
    float run = 0.f, runc = 0.f;
    for (int i = 0; i < 256; ++i) {
        const int b = bb[i];
        if (b < 0) break;
        if (b != cur) {
            atomicAdd(&sums[(size_t)cur * 128 + tid], run);
            if (tid == 0) atomicAdd(&cnt[cur], runc);
            run = 0.f; runc = 0.f; cur = b;
        }
        run += h_node[(size_t)(n0 + i) * 128 + tid];
        runc += 1.f;
    }
    atomicAdd(&sums[(size_t)cur * 128 + tid], run);
    if (tid == 0) atomicAdd(&cnt[cur], runc);
}

__global__ __launch_bounds__(256) void final_kernel(
    const float* __restrict__ sums, const float* __restrict__ cnt,
    const float* __restrict__ out_w, const float* __restrict__ out_b,
    float* __restrict__ out)
{
    const int g = threadIdx.x;
    const float c = fmaxf(cnt[g], 1.0f);
    float acc = 0.f;
    for (int jj = 0; jj < 128; ++jj) acc = fmaf(sums[(size_t)g * 128 + jj], out_w[jj], acc);
    out[g] = acc / c + out_b[0];
}

__global__ void zero_out_kernel(float* out, int n) {
    int i = blockIdx.x * 256 + threadIdx.x;
    if (i < n) out[i] = 0.f;
}

// ---------------------------------------------------------------------------

extern "C" void kernel_launch(void* const* d_in, const int* in_sizes, int n_in,
                              void* d_out, int out_size, void* d_ws, size_t ws_size,
                              hipStream_t stream)
{
    const int*   z          = (const int*)  d_in[0];
    const float* pos        = (const float*)d_in[1];
    const int*   batch      = (const int*)  d_in[2];
    const int*   eidx       = (const int*)  d_in[3];
    const float* atom_table = (const float*)d_in[4];
    const float* atom_w     = (const float*)d_in[5];
    const float* atom_b     = (const float*)d_in[6];
    const float* edge_emb_w = (const float*)d_in[7];
    const float* edge_emb_b = (const float*)d_in[8];
    const float* edge_w0    = (const float*)d_in[9];    // [5][384][128]
    const float* edge_b0    = (const float*)d_in[10];   // [5][128]
    const float* edge_w     = (const float*)d_in[11];   // [5][4][128][128]
    const float* edge_b     = (const float*)d_in[12];   // [5][4][128]
    const float* node_w     = (const float*)d_in[13];   // [5][128][128]
    const float* node_b     = (const float*)d_in[14];   // [5][128]
    const float* out_w      = (const float*)d_in[15];
    const float* out_b      = (const float*)d_in[16];
    const int* row = eidx;
    const int* col = eidx + N_EDGES_;

    // ws layout: h_node f32 | agg f32 | sums f32 | cnt f32 | h_edge bf16 | Wp bf16
    float* ws     = (float*)d_ws;
    float* h_node = ws;
    float* aggb   = h_node + (size_t)N_NODES_ * EMB;
    float* sums   = aggb   + (size_t)N_NODES_ * EMB;
    float* cnt    = sums   + (size_t)N_GRAPH_ * EMB;
    unsigned short* h_edge = (unsigned short*)(cnt + N_GRAPH_);
    unsigned short* Wp     = h_edge + (size_t)N_EDGES_ * EMB;

    const size_t headB     = ((size_t)N_NODES_ * EMB * 2 + (size_t)N_GRAPH_ * EMB + N_GRAPH_) * 4;
    const size_t need_bf16 = headB + (size_t)N_EDGES_ * EMB * 2;          // 256,132,096
    const size_t need_mfma = need_bf16 + (size_t)5 * 114688 * 2;          // +2,293,760

    if (ws_size < need_bf16) {
        zero_out_kernel<<<1, 256, 0, stream>>>((float*)d_out, N_GRAPH_);
        return;
    }
    const bool use_mfma = (ws_size >= need_mfma);

    const int grid_rows = (N_NODES_ + 31) / 32;

    row_gemm_kernel<1, 0, 0><<<grid_rows, 256, 0, stream>>>(atom_table, z, atom_w, atom_b, h_node, N_NODES_);
    edge_embed_kernel<<<1024, 256, 0, stream>>>(pos, row, col, edge_emb_w, edge_emb_b, h_edge, N_EDGES_);
    if (use_mfma)
        pack_w_kernel<<<200, 256, 0, stream>>>(edge_w0, edge_w, Wp);

    for (int l = 0; l < NLAYER_; ++l) {
        (void)hipMemsetAsync(aggb, 0, (size_t)N_NODES_ * EMB * sizeof(float), stream);
        if (use_mfma) {
            edge_mlp_mfma_kernel<<<N_EDGES_ / 64, 256, 0, stream>>>(
                h_node, h_edge, aggb, row, col,
                Wp + (size_t)l * 114688,
                edge_b0 + (size_t)l * 128, edge_b + (size_t)l * 4 * 128);
        } else {
            edge_mlp_fallback_kernel<<<N_EDGES_ / 32, 256, 0, stream>>>(
                h_node, h_edge, aggb, row, col,
                edge_w0 + (size_t)l * 384 * 128, edge_b0 + (size_t)l * 128,
                edge_w  + (size_t)l * 4 * 128 * 128, edge_b + (size_t)l * 4 * 128);
        }
        row_gemm_kernel<0, 1, 1><<<grid_rows, 256, 0, stream>>>(
            aggb, nullptr, node_w + (size_t)l * 128 * 128, node_b + (size_t)l * 128, h_node, N_NODES_);
    }

    (void)hipMemsetAsync(sums, 0, ((size_t)N_GRAPH_ * EMB + N_GRAPH_) * sizeof(float), stream);
    pool_kernel<<<(N_NODES_ + 255) / 256, 128, 0, stream>>>(h_node, batch, sums, cnt, N_NODES_);
    final_kernel<<<1, 256, 0, stream>>>(sums, cnt, out_w, out_b, (float*)d_out);
}

// Round 5
// 3554.995 us; speedup vs baseline: 4.5915x; 4.3572x over previous
//
#include <hip/hip_runtime.h>

#define EMB      128
#define N_NODES_ 50000
#define N_EDGES_ 800000
#define N_GRAPH_ 256
#define NLAYER_  5

typedef short short8 __attribute__((ext_vector_type(8)));
typedef float floatx4 __attribute__((ext_vector_type(4)));

__device__ __forceinline__ float silu_f(float x) {
    return x / (1.0f + __expf(-x));
}
__device__ __forceinline__ float bf2f(unsigned short h) {
    return __uint_as_float(((unsigned)h) << 16);
}
__device__ __forceinline__ unsigned short f2bf(float f) {
    unsigned u = __float_as_uint(f);
    unsigned r = 0x7FFFu + ((u >> 16) & 1u);
    return (unsigned short)((u + r) >> 16);
}

// ---------------------------------------------------------------------------
// Weight packing: fp32 [K][128] -> bf16 B-fragment order for 16x16x32 MFMA.
// packed[tile t][kb][lane][j] = W[kb*32 + (lane>>4)*8 + j][t*16 + (lane&15)]
// ---------------------------------------------------------------------------
__global__ __launch_bounds__(256) void pack_w_kernel(
    const float* __restrict__ edge_w0, const float* __restrict__ edge_w,
    unsigned short* __restrict__ Wp)
{
    const int bid = blockIdx.x;            // 200 = 5 layers * 5 stages * 8 tiles
    const int l = bid / 40, r = bid % 40, s = r / 8, t = r % 8;
    const int Kb = (s == 0) ? 12 : 4;
    const float* __restrict__ src = (s == 0)
        ? edge_w0 + (size_t)l * 384 * 128
        : edge_w  + ((size_t)l * 4 + (s - 1)) * 128 * 128;
    unsigned short* __restrict__ dst =
        Wp + (size_t)l * 114688 + ((s == 0) ? 0 : (49152 + (s - 1) * 16384)) + (size_t)t * Kb * 512;
    const int n = Kb * 512;
    for (int p = threadIdx.x; p < n; p += 256) {
        const int j = p & 7, lane = (p >> 3) & 63, kb = p >> 9;
        const int k  = kb * 32 + ((lane >> 4) << 3) + j;
        const int nn = t * 16 + (lane & 15);
        dst[p] = f2bf(src[(size_t)k * 128 + nn]);
    }
}

// ---------------------------------------------------------------------------
// MFMA edge MLP: 64 edges/block, 4 waves, mfma_f32_16x16x32_bf16.
// Epilogue split in two phases:
//  phase 1: h_edge_new = old + m, store to global AND back into LDS A.
//  phase 2: scatter atomics with LANE-CONSECUTIVE addresses (16 lanes / 64B
//           line) — round-4 counters showed atomic HBM-write traffic scales
//           with lines-touched-per-instruction (2 lanes/line -> 3.4 GB vs
//           4 lanes/line -> 1.8 GB); this mapping gives the fp32 maximum.
// ---------------------------------------------------------------------------
__global__ __launch_bounds__(256, 3) void edge_mlp_mfma_kernel(
    const float* __restrict__ h_node, unsigned short* __restrict__ h_edge,
    float* __restrict__ agg,
    const int* __restrict__ row, const int* __restrict__ col,
    const unsigned short* __restrict__ Wp,     // this layer's packed weights
    const float* __restrict__ b0, const float* __restrict__ bh)
{
    __shared__ unsigned short A[64][392];      // 50,176 B; rows 784 B (16B-mult)
    __shared__ int rv[64], cv[64];
    const int tid = threadIdx.x;
    const int e0 = blockIdx.x * 64;

    if (tid < 64) { rv[tid] = row[e0 + tid]; cv[tid] = col[e0 + tid]; }
    __syncthreads();

    // stage concat -> bf16 LDS: cols [0,128)=h_edge, [128,256)=h_node[row], [256,384)=h_node[col]
    for (int idx = tid; idx < 64 * 48; idx += 256) {
        const int t  = idx / 48;
        const int k8 = (idx % 48) << 3;
        if (k8 < 128) {
            *(short8*)&A[t][k8] = *(const short8*)&h_edge[(size_t)(e0 + t) * 128 + k8];
        } else {
            const float* src = (k8 < 256) ? &h_node[(size_t)rv[t] * 128 + (k8 - 128)]
                                          : &h_node[(size_t)cv[t] * 128 + (k8 - 256)];
            const float4 f0 = *(const float4*)src;
            const float4 f1 = *(const float4*)(src + 4);
            short8 v;
            v[0] = (short)f2bf(f0.x); v[1] = (short)f2bf(f0.y);
            v[2] = (short)f2bf(f0.z); v[3] = (short)f2bf(f0.w);
            v[4] = (short)f2bf(f1.x); v[5] = (short)f2bf(f1.y);
            v[6] = (short)f2bf(f1.z); v[7] = (short)f2bf(f1.w);
            *(short8*)&A[t][k8] = v;
        }
    }
    __syncthreads();

    const int lane = tid & 63;
    const int wv   = tid >> 6;
    const int lr   = lane & 15;   // A row-in-tile / C col
    const int lg   = lane >> 4;   // k-group / C row-group
    const int nt0  = 2 * wv, nt1 = 2 * wv + 1;

    for (int s = 0; s < 5; ++s) {
        const int Kb = (s == 0) ? 12 : 4;
        const unsigned short* __restrict__ Ws =
            Wp + ((s == 0) ? 0 : (49152 + (s - 1) * 16384));
        const float* __restrict__ bias = (s == 0) ? b0 : (bh + (s - 1) * 128);

        floatx4 acc[4][2];
#pragma unroll
        for (int mt = 0; mt < 4; ++mt) {
            acc[mt][0] = (floatx4){0.f, 0.f, 0.f, 0.f};
            acc[mt][1] = (floatx4){0.f, 0.f, 0.f, 0.f};
        }

        const unsigned short* bptr0 = Ws + ((size_t)(nt0 * Kb) * 64 + lane) * 8;
        const unsigned short* bptr1 = Ws + ((size_t)(nt1 * Kb) * 64 + lane) * 8;
#pragma unroll 2
        for (int kb = 0; kb < Kb; ++kb) {
            const short8 bf0 = *(const short8*)(bptr0 + (size_t)kb * 512);
            const short8 bf1 = *(const short8*)(bptr1 + (size_t)kb * 512);
#pragma unroll
            for (int mt = 0; mt < 4; ++mt) {
                const short8 af = *(const short8*)&A[mt * 16 + lr][kb * 32 + lg * 8];
                acc[mt][0] = __builtin_amdgcn_mfma_f32_16x16x32_bf16(af, bf0, acc[mt][0], 0, 0, 0);
                acc[mt][1] = __builtin_amdgcn_mfma_f32_16x16x32_bf16(af, bf1, acc[mt][1], 0, 0, 0);
            }
        }
        const float bn0 = bias[nt0 * 16 + lr];
        const float bn1 = bias[nt1 * 16 + lr];
        __syncthreads();   // all LDS reads of this stage done before overwrite
#pragma unroll
        for (int mt = 0; mt < 4; ++mt)
#pragma unroll
            for (int r4 = 0; r4 < 4; ++r4) {
                const int m = mt * 16 + lg * 4 + r4;
                A[m][nt0 * 16 + lr] = f2bf(silu_f(acc[mt][0][r4] + bn0));
                A[m][nt1 * 16 + lr] = f2bf(silu_f(acc[mt][1][r4] + bn1));
            }
        __syncthreads();
    }

    // --- epilogue phase 1: h_edge_new = old + m; store global + back to LDS
    for (int idx = tid; idx < 64 * 16; idx += 256) {
        const int t  = idx >> 4;
        const int k8 = (idx & 15) << 3;
        const size_t eoff = (size_t)(e0 + t) * 128 + k8;
        const short8 mv = *(const short8*)&A[t][k8];
        const short8 ov = *(const short8*)&h_edge[eoff];
        short8 sv;
#pragma unroll
        for (int i = 0; i < 8; ++i) {
            const float he = bf2f((unsigned short)ov[i]) + bf2f((unsigned short)mv[i]);
            sv[i] = (short)f2bf(he);
        }
        *(short8*)&h_edge[eoff] = sv;
        *(short8*)&A[t][k8] = sv;          // same (t,k8) chunk this thread read
    }
    __syncthreads();

    // --- epilogue phase 2: lane-consecutive scatter atomics
    // wave instruction = one edge row, 64 consecutive floats (4 lines, 16 lanes/line)
#pragma unroll 8
    for (int w = 0; w < 32; ++w) {
        const int g = w * 256 + tid;
        const int t = g >> 7;
        const int c = g & 127;
        atomicAdd(&agg[(size_t)rv[t] * 128 + c], bf2f(A[t][c]));
    }
}

// ---------------------------------------------------------------------------
// Fallback VALU edge MLP (bf16 state) for small-ws case.
// ---------------------------------------------------------------------------
__device__ __forceinline__ float4 ld_bf4(const unsigned short* p) {
    ushort4 u = *(const ushort4*)p;
    return make_float4(bf2f(u.x), bf2f(u.y), bf2f(u.z), bf2f(u.w));
}
__device__ __forceinline__ void st_bf4(unsigned short* p, float4 v) {
    *(ushort4*)p = make_ushort4(f2bf(v.x), f2bf(v.y), f2bf(v.z), f2bf(v.w));
}

__device__ __forceinline__ void fma4x4(const float4 a[4], const float4& w0, const float4& w1,
                                       const float4& w2, const float4& w3, float acc[4][4]) {
#pragma unroll
    for (int i = 0; i < 4; ++i) {
        acc[i][0] = fmaf(a[i].x, w0.x, fmaf(a[i].y, w1.x, fmaf(a[i].z, w2.x, fmaf(a[i].w, w3.x, acc[i][0]))));
        acc[i][1] = fmaf(a[i].x, w0.y, fmaf(a[i].y, w1.y, fmaf(a[i].z, w2.y, fmaf(a[i].w, w3.y, acc[i][1]))));
        acc[i][2] = fmaf(a[i].x, w0.z, fmaf(a[i].y, w1.z, fmaf(a[i].z, w2.z, fmaf(a[i].w, w3.z, acc[i][2]))));
        acc[i][3] = fmaf(a[i].x, w0.w, fmaf(a[i].y, w1.w, fmaf(a[i].z, w2.w, fmaf(a[i].w, w3.w, acc[i][3]))));
    }
}

__global__ __launch_bounds__(256, 2) void edge_mlp_fallback_kernel(
    const float* __restrict__ h_node, unsigned short* __restrict__ h_edge,
    float* __restrict__ agg,
    const int* __restrict__ row, const int* __restrict__ col,
    const float* __restrict__ W0, const float* __restrict__ b0,
    const float* __restrict__ Wh, const float* __restrict__ bh)
{
    __shared__ __align__(16) float A[32][388];
    __shared__ int rv[32], cv[32];
    const int tid = threadIdx.x;
    const int e0 = blockIdx.x * 32;

    if (tid < 32) { rv[tid] = row[e0 + tid]; cv[tid] = col[e0 + tid]; }
    __syncthreads();

    for (int idx = tid; idx < 32 * 96; idx += 256) {
        int t = idx / 96;
        int k = (idx - t * 96) << 2;
        float4 v;
        if (k < 128)      v = ld_bf4(&h_edge[(size_t)(e0 + t) * 128 + k]);
        else if (k < 256) v = *(const float4*)&h_node[(size_t)rv[t] * 128 + (k - 128)];
        else              v = *(const float4*)&h_node[(size_t)cv[t] * 128 + (k - 256)];
        *(float4*)&A[t][k] = v;
    }
    __syncthreads();

    const int r = tid >> 5, c = tid & 31;
    const int t0 = r << 2, j0 = c << 2;
    float res[4][4];

    for (int stage = 0; stage < 5; ++stage) {
        const float* __restrict__ W  = (stage == 0) ? W0 : (Wh + (size_t)(stage - 1) * 128 * 128);
        const float* __restrict__ bb = (stage == 0) ? b0 : (bh + (size_t)(stage - 1) * 128);
        const int K = (stage == 0) ? 384 : 128;

        float acc[4][4] = {{0.f, 0.f, 0.f, 0.f}};
#pragma unroll 2
        for (int kk = 0; kk < K; kk += 4) {
            float4 a[4];
#pragma unroll
            for (int i = 0; i < 4; ++i) a[i] = *(const float4*)&A[t0 + i][kk];
            const float4 w0 = *(const float4*)&W[(size_t)(kk + 0) * 128 + j0];
            const float4 w1 = *(const float4*)&W[(size_t)(kk + 1) * 128 + j0];
            const float4 w2 = *(const float4*)&W[(size_t)(kk + 2) * 128 + j0];
            const float4 w3 = *(const float4*)&W[(size_t)(kk + 3) * 128 + j0];
            fma4x4(a, w0, w1, w2, w3, acc);
        }
        const float4 bv = *(const float4*)&bb[j0];
        const float bias[4] = {bv.x, bv.y, bv.z, bv.w};
#pragma unroll
        for (int i = 0; i < 4; ++i)
#pragma unroll
            for (int jj = 0; jj < 4; ++jj)
                res[i][jj] = silu_f(acc[i][jj] + bias[jj]);
        if (stage < 4) {
            __syncthreads();
#pragma unroll
            for (int i = 0; i < 4; ++i)
                *(float4*)&A[t0 + i][j0] = make_float4(res[i][0], res[i][1], res[i][2], res[i][3]);
            __syncthreads();
        }
    }

#pragma unroll
    for (int i = 0; i < 4; ++i) {
        const size_t eoff = (size_t)(e0 + t0 + i) * 128 + j0;
        float4 he = ld_bf4(&h_edge[eoff]);
        he.x += res[i][0]; he.y += res[i][1]; he.z += res[i][2]; he.w += res[i][3];
        st_bf4(&h_edge[eoff], he);
        float* ap = &agg[(size_t)rv[t0 + i] * 128 + j0];
        atomicAdd(ap + 0, he.x);
        atomicAdd(ap + 1, he.y);
        atomicAdd(ap + 2, he.z);
        atomicAdd(ap + 3, he.w);
    }
}

// ---------------------------------------------------------------------------
// Generic [N,128] @ [128,128] (+bias, optional gather / silu / residual-add).
// ---------------------------------------------------------------------------
template <int GATHER, int RESID, int SILU>
__global__ __launch_bounds__(256, 4) void row_gemm_kernel(
    const float* __restrict__ src, const int* __restrict__ gidx,
    const float* __restrict__ W, const float* __restrict__ bias,
    float* __restrict__ dst, int N)
{
    __shared__ __align__(16) float A[32][132];
    const int tid = threadIdx.x;
    const int n0 = blockIdx.x * 32;

    for (int idx = tid; idx < 32 * 32; idx += 256) {
        int t = idx >> 5, k = (idx & 31) << 2;
        int n = n0 + t;
        float4 v = make_float4(0.f, 0.f, 0.f, 0.f);
        if (n < N) {
            int rr = GATHER ? gidx[n] : n;
            v = *(const float4*)&src[(size_t)rr * 128 + k];
        }
        *(float4*)&A[t][k] = v;
    }
    __syncthreads();

    const int r = tid >> 5, c = tid & 31;
    const int t0 = r << 2, j0 = c << 2;
    float acc[4][4] = {{0.f, 0.f, 0.f, 0.f}};
#pragma unroll 2
    for (int kk = 0; kk < 128; kk += 4) {
        float4 a[4];
#pragma unroll
        for (int i = 0; i < 4; ++i) a[i] = *(const float4*)&A[t0 + i][kk];
        const float4 w0 = *(const float4*)&W[(size_t)(kk + 0) * 128 + j0];
        const float4 w1 = *(const float4*)&W[(size_t)(kk + 1) * 128 + j0];
        const float4 w2 = *(const float4*)&W[(size_t)(kk + 2) * 128 + j0];
        const float4 w3 = *(const float4*)&W[(size_t)(kk + 3) * 128 + j0];
        fma4x4(a, w0, w1, w2, w3, acc);
    }
    const float4 bv = *(const float4*)&bias[j0];
    const float bias4[4] = {bv.x, bv.y, bv.z, bv.w};
#pragma unroll
    for (int i = 0; i < 4; ++i) {
        int n = n0 + t0 + i;
        if (n >= N) continue;
        float x[4];
#pragma unroll
        for (int jj = 0; jj < 4; ++jj) {
            x[jj] = acc[i][jj] + bias4[jj];
            if (SILU) x[jj] = silu_f(x[jj]);
        }
        const size_t off = (size_t)n * 128 + j0;
        float4 o = make_float4(x[0], x[1], x[2], x[3]);
        if (RESID) {
            float4 d = *(const float4*)&dst[off];
            o.x += d.x; o.y += d.y; o.z += d.z; o.w += d.w;
        }
        *(float4*)&dst[off] = o;
    }
}

// ---------------------------------------------------------------------------
// Edge embedding: d = |pos[row]-pos[col]|, 32 gaussians, @ edge_emb_w + b.
// ---------------------------------------------------------------------------
__global__ __launch_bounds__(256) void edge_embed_kernel(
    const float* __restrict__ pos, const int* __restrict__ row, const int* __restrict__ col,
    const float* __restrict__ Wemb, const float* __restrict__ bemb,
    unsigned short* __restrict__ h_edge, int E)
{
    __shared__ __align__(16) float Ws[32][128];
    __shared__ float bas[8][32];
    const int tid = threadIdx.x;
    {
        const float4* Wv = (const float4*)Wemb;
        float4* Wsv = (float4*)Ws;
        for (int idx = tid; idx < 1024; idx += 256) Wsv[idx] = Wv[idx];
    }
    const int g = tid >> 5, k = tid & 31;
    const int j = tid & 127, gh = tid >> 7;
    const float mu   = (float)k * (5.0f / 31.0f);
    const float invs = 32.0f / 5.0f;

    for (int eb = blockIdx.x * 8; eb < E; eb += gridDim.x * 8) {
        __syncthreads();
        const int e = eb + g;
        const int rr = row[e], cc = col[e];
        const float dx = pos[rr * 3 + 0] - pos[cc * 3 + 0];
        const float dy = pos[rr * 3 + 1] - pos[cc * 3 + 1];
        const float dz = pos[rr * 3 + 2] - pos[cc * 3 + 2];
        const float d = sqrtf(dx * dx + dy * dy + dz * dz);
        const float t = (d - mu) * invs;
        bas[g][k] = __expf(-0.5f * t * t);
        __syncthreads();
#pragma unroll
        for (int gg = 0; gg < 4; ++gg) {
            const int ge = (gh << 2) + gg;
            float h = bemb[j];
#pragma unroll
            for (int kk = 0; kk < 32; ++kk) h = fmaf(bas[ge][kk], Ws[kk][j], h);
            h_edge[(size_t)(eb + ge) * 128 + j] = f2bf(h);
        }
    }
}

// ---------------------------------------------------------------------------
// Graph pooling + output head.
// ---------------------------------------------------------------------------
__global__ __launch_bounds__(128) void pool_kernel(
    const float* __restrict__ h_node, const int* __restrict__ batch,
    float* __restrict__ sums, float* __restrict__ cnt, int N)
{
    __shared__ int bb[256];
    const int tid = threadIdx.x;
    const int n0 = blockIdx.x * 256;
    for (int idx = tid; idx < 256; idx += 128) {
        int n = n0 + idx;
        bb[idx] = (n < N) ? batch[n] : -1;
    }
    __syncthreads();
    int cur = bb[0];
    float run = 0.f, runc = 0.f;
    for (int i = 0; i < 256; ++i) {
        const int b = bb[i];
        if (b < 0) break;
        if (b != cur) {
            atomicAdd(&sums[(size_t)cur * 128 + tid], run);
            if (tid == 0) atomicAdd(&cnt[cur], runc);
            run = 0.f; runc = 0.f; cur = b;
        }
        run += h_node[(size_t)(n0 + i) * 128 + tid];
        runc += 1.f;
    }
    atomicAdd(&sums[(size_t)cur * 128 + tid], run);
    if (tid == 0) atomicAdd(&cnt[cur], runc);
}

__global__ __launch_bounds__(256) void final_kernel(
    const float* __restrict__ sums, const float* __restrict__ cnt,
    const float* __restrict__ out_w, const float* __restrict__ out_b,
    float* __restrict__ out)
{
    const int g = threadIdx.x;
    const float c = fmaxf(cnt[g], 1.0f);
    float acc = 0.f;
    for (int jj = 0; jj < 128; ++jj) acc = fmaf(sums[(size_t)g * 128 + jj], out_w[jj], acc);
    out[g] = acc / c + out_b[0];
}

__global__ void zero_out_kernel(float* out, int n) {
    int i = blockIdx.x * 256 + threadIdx.x;
    if (i < n) out[i] = 0.f;
}

// ---------------------------------------------------------------------------

extern "C" void kernel_launch(void* const* d_in, const int* in_sizes, int n_in,
                              void* d_out, int out_size, void* d_ws, size_t ws_size,
                              hipStream_t stream)
{
    const int*   z          = (const int*)  d_in[0];
    const float* pos        = (const float*)d_in[1];
    const int*   batch      = (const int*)  d_in[2];
    const int*   eidx       = (const int*)  d_in[3];
    const float* atom_table = (const float*)d_in[4];
    const float* atom_w     = (const float*)d_in[5];
    const float* atom_b     = (const float*)d_in[6];
    const float* edge_emb_w = (const float*)d_in[7];
    const float* edge_emb_b = (const float*)d_in[8];
    const float* edge_w0    = (const float*)d_in[9];    // [5][384][128]
    const float* edge_b0    = (const float*)d_in[10];   // [5][128]
    const float* edge_w     = (const float*)d_in[11];   // [5][4][128][128]
    const float* edge_b     = (const float*)d_in[12];   // [5][4][128]
    const float* node_w     = (const float*)d_in[13];   // [5][128][128]
    const float* node_b     = (const float*)d_in[14];   // [5][128]
    const float* out_w      = (const float*)d_in[15];
    const float* out_b      = (const float*)d_in[16];
    const int* row = eidx;
    const int* col = eidx + N_EDGES_;

    // ws layout: h_node f32 | agg f32 | sums f32 | cnt f32 | h_edge bf16 | Wp bf16
    float* ws     = (float*)d_ws;
    float* h_node = ws;
    float* aggb   = h_node + (size_t)N_NODES_ * EMB;
    float* sums   = aggb   + (size_t)N_NODES_ * EMB;
    float* cnt    = sums   + (size_t)N_GRAPH_ * EMB;
    unsigned short* h_edge = (unsigned short*)(cnt + N_GRAPH_);
    unsigned short* Wp     = h_edge + (size_t)N_EDGES_ * EMB;

    const size_t headB     = ((size_t)N_NODES_ * EMB * 2 + (size_t)N_GRAPH_ * EMB + N_GRAPH_) * 4;
    const size_t need_bf16 = headB + (size_t)N_EDGES_ * EMB * 2;          // 256,132,096
    const size_t need_mfma = need_bf16 + (size_t)5 * 114688 * 2;          // +1,146,880

    if (ws_size < need_bf16) {
        zero_out_kernel<<<1, 256, 0, stream>>>((float*)d_out, N_GRAPH_);
        return;
    }
    const bool use_mfma = (ws_size >= need_mfma);

    const int grid_rows = (N_NODES_ + 31) / 32;

    row_gemm_kernel<1, 0, 0><<<grid_rows, 256, 0, stream>>>(atom_table, z, atom_w, atom_b, h_node, N_NODES_);
    edge_embed_kernel<<<1024, 256, 0, stream>>>(pos, row, col, edge_emb_w, edge_emb_b, h_edge, N_EDGES_);
    if (use_mfma)
        pack_w_kernel<<<200, 256, 0, stream>>>(edge_w0, edge_w, Wp);

    for (int l = 0; l < NLAYER_; ++l) {
        (void)hipMemsetAsync(aggb, 0, (size_t)N_NODES_ * EMB * sizeof(float), stream);
        if (use_mfma) {
            edge_mlp_mfma_kernel<<<N_EDGES_ / 64, 256, 0, stream>>>(
                h_node, h_edge, aggb, row, col,
                Wp + (size_t)l * 114688,
                edge_b0 + (size_t)l * 128, edge_b + (size_t)l * 4 * 128);
        } else {
            edge_mlp_fallback_kernel<<<N_EDGES_ / 32, 256, 0, stream>>>(
                h_node, h_edge, aggb, row, col,
                edge_w0 + (size_t)l * 384 * 128, edge_b0 + (size_t)l * 128,
                edge_w  + (size_t)l * 4 * 128 * 128, edge_b + (size_t)l * 4 * 128);
        }
        row_gemm_kernel<0, 1, 1><<<grid_rows, 256, 0, stream>>>(
            aggb, nullptr, node_w + (size_t)l * 128 * 128, node_b + (size_t)l * 128, h_node, N_NODES_);
    }

    (void)hipMemsetAsync(sums, 0, ((size_t)N_GRAPH_ * EMB + N_GRAPH_) * sizeof(float), stream);
    pool_kernel<<<(N_NODES_ + 255) / 256, 128, 0, stream>>>(h_node, batch, sums, cnt, N_NODES_);
    final_kernel<<<1, 256, 0, stream>>>(sums, cnt, out_w, out_b, (float*)d_out);
}